// Round 7
// baseline (92.550 us; speedup 1.0000x reference)
//
#include <hip/hip_runtime.h>
#include <stdint.h>

typedef float  f32x4 __attribute__((ext_vector_type(4)));
typedef short  s16x8 __attribute__((ext_vector_type(8)));
typedef short  s16x4 __attribute__((ext_vector_type(4)));
typedef unsigned int uint32;

#define B_ 16
#define N_ 256
#define T_ 64
#define F_ 128
#define KT 32
#define NT 8   /* K tiles: 8*32 = 256 */

// LDS layout (bytes), UNPADDED 16x16 bf16 subtiles (512 B).
// X: 2-tile double buffer (2 x 8 KB). W: ONE 256l x 32k tile (16 KB).
// Total 32768 B -> LDS permits 5 blocks/CU; VGPR (~80) permits 2; grid 4.
// (R6 lesson: exact 2x81920 = full-pool fit does NOT co-schedule; leave slack.)
#define SUBT 512
#define X_BUF_STR (16 * SUBT)               /* 8192 per k-tile buffer */
#define X_OFF 0
#define W_OFF (2 * X_BUF_STR)               /* 16384 */
#define LDS_SZ (W_OFF + 32 * SUBT)          /* 32768 */

#define TRREAD(dst, addr) \
  asm volatile("ds_read_b64_tr_b16 %0, %1" : "=v"(dst) : "v"(addr))

#define LGKM_FENCE() asm volatile("s_waitcnt lgkmcnt(0)" ::: "memory")
#define BAR()                                    \
  do {                                           \
    LGKM_FENCE();                                \
    __builtin_amdgcn_s_barrier();                \
    asm volatile("" ::: "memory");               \
  } while (0)

__device__ __forceinline__ unsigned short f2bf(float f) {
  union { float f; unsigned int u; } v; v.f = f;
  unsigned int u = v.u;
  return (unsigned short)((u + 0x7fffu + ((u >> 16) & 1u)) >> 16);
}

// fwTb[c][l] = bf16(full_weight[l][c])  (256x256, lives in d_ws, L2-resident)
__global__ void wtrans_kernel(const float* __restrict__ fw,
                              unsigned short* __restrict__ fwTb) {
  int c = blockIdx.x;
  int l = threadIdx.x;
  fwTb[c * N_ + l] = f2bf(fw[l * N_ + c]);
}

// launch_bounds(512, 2): 256-VGPR cap; compiler lands ~80 (R4/R6) -> 16
// waves/CU natural -> 2 blocks/CU. DO NOT raise the 2nd arg: (512,4)
// empirically clamps to 64 VGPR -> acc spills -> 3-5x slowdown (R2/R5).
__global__ __launch_bounds__(512, 2) void fused_kernel(
    const float* __restrict__ x,
    const int* __restrict__ entry,
    const int* __restrict__ job,
    const unsigned short* __restrict__ fwTb,
    float* __restrict__ out) {
  __shared__ __align__(16) char smem[LDS_SZ];
  const uint32 lds_u = (uint32)(uintptr_t)(&smem[0]);

  const int tid = threadIdx.x;
  const int bid = blockIdx.x;
  const int b = bid >> 6;
  const int t = bid & 63;

  const int wk  = tid & 31;   // this thread's k-column within every tile
  const int wlg = tid >> 5;   // this thread's 16-row l group (0..15)

  // ---- issue per-thread E/J id loads FIRST (oldest in vmcnt queue) ----
  int er[8], jr[8], jlr[16];
#pragma unroll
  for (int i = 0; i < 8; ++i) {
    er[i] = entry[(b * N_ + i * KT + wk) * T_ + t];
    jr[i] = job[(b * N_ + i * KT + wk) * T_ + t];
  }
#pragma unroll
  for (int i = 0; i < 16; ++i)
    jlr[i] = job[(b * N_ + wlg * 16 + i) * T_ + t];

  // ---- issue X(0) loads ----
  const int xk  = tid >> 4;          // 0..31 (k offset within a tile)
  const int xf0 = (tid & 15) << 3;   // 0,8,...,120
  const float* xsrc = x + ((b * N_ + xk) * T_ + t) * F_ + xf0;
  f32x4 c0a = *(const f32x4*)(xsrc);
  f32x4 c0b = *(const f32x4*)(xsrc + 4);

  // ---- pack ids into registers (waits only on the early id loads) ----
  uint32 ep0 = 0, ep1 = 0, jp0 = 0, jp1 = 0;
#pragma unroll
  for (int i = 0; i < 4; ++i) {
    ep0 |= ((uint32)(er[i] & 255)) << (8 * i);
    ep1 |= ((uint32)(er[i + 4] & 255)) << (8 * i);
    jp0 |= ((uint32)(jr[i] & 255)) << (8 * i);
    jp1 |= ((uint32)(jr[i + 4] & 255)) << (8 * i);
  }
  uint64_t jl80 = 0, jl81 = 0;
#pragma unroll
  for (int i = 0; i < 8; ++i) {
    jl80 |= ((uint64_t)(jlr[i] & 255)) << (8 * i);
    jl81 |= ((uint64_t)(jlr[i + 8] & 255)) << (8 * i);
  }

  // ---- W(0) gather from L2 + mask + store ----
  const uint32 wwr_base =
      (uint32)(((wk >> 4) * 16 + wlg) * SUBT + (wk & 15) * 32);
  {
    const int ev = (int)(ep0 & 255);
    const unsigned char gjk = (unsigned char)(jp0 & 255);
    const unsigned short* wrow = fwTb + ev * N_ + wlg * 16;
    s16x8 gv0 = *(const s16x8*)(wrow);
    s16x8 gv1 = *(const s16x8*)(wrow + 8);
    s16x8 m0, m1;
#pragma unroll
    for (int i = 0; i < 8; ++i) {
      const unsigned char a0 = (unsigned char)(jl80 >> (8 * i));
      const unsigned char a1 = (unsigned char)(jl81 >> (8 * i));
      m0[i] = (gjk != 0 && a0 == gjk) ? gv0[i] : (short)0;
      m1[i] = (gjk != 0 && a1 == gjk) ? gv1[i] : (short)0;
    }
    *(s16x8*)(smem + W_OFF + wwr_base) = m0;
    *(s16x8*)(smem + W_OFF + wwr_base + 16) = m1;
  }

  // ---- X(0) convert + stage into buf 0 ----
  const uint32 xdst_in = (uint32)((((xk >> 4) * 8 + (xf0 >> 4)) * SUBT) +
                                  ((xk & 15) * 32) + ((xf0 & 15) * 2));
  {
    s16x8 pk;
#pragma unroll
    for (int j = 0; j < 4; ++j) {
      pk[j]     = (short)f2bf(c0a[j]);
      pk[j + 4] = (short)f2bf(c0b[j]);
    }
    *(s16x8*)(smem + X_OFF + xdst_in) = pk;
  }
  BAR();  // X(0) + W(0) ready

  const int lane = tid & 63;
  const int wid  = tid >> 6;
  const int wl   = wid & 3;   // wave's 64-l sub-tile (0..3)
  const int wf   = wid >> 2;  // wave's 64-f sub-tile (0..1)

  f32x4 acc[4][4];
#pragma unroll
  for (int i = 0; i < 4; ++i)
#pragma unroll
    for (int j = 0; j < 4; ++j) acc[i][j] = (f32x4){0.f, 0.f, 0.f, 0.f};

  for (int kt = 0; kt < NT; ++kt) {
    // ---- issue X(kt+1) global loads first (HBM latency hides under
    //      the W-gather + tr_read + MFMA below) ----
    f32x4 p0, p1;
    if (kt + 1 < NT) {
      const float* src =
          x + ((b * N_ + (kt + 1) * KT + xk) * T_ + t) * F_ + xf0;
      p0 = *(const f32x4*)(src);
      p1 = *(const f32x4*)(src + 4);
    }

    // ---- prefetch W(kt+1) gather into regs (ids from regs, no LDS dep) ----
    s16x8 pv0, pv1;
    unsigned char pjk = 0;
    if (kt + 1 < NT) {
      const uint32 esel = (kt + 1 < 4) ? ep0 : ep1;
      const uint32 jsel = (kt + 1 < 4) ? jp0 : jp1;
      const int sh = ((kt + 1) & 3) * 8;
      const int ev = (int)((esel >> sh) & 255);
      pjk = (unsigned char)((jsel >> sh) & 255);
      const unsigned short* wrow = fwTb + ev * N_ + wlg * 16;
      pv0 = *(const s16x8*)(wrow);
      pv1 = *(const s16x8*)(wrow + 8);
    }

    // ---- fragments: W from the single buffer, X from buf (kt&1) ----
    s16x4 ah[4][2], bh[4][2];
    {
      const uint32 wbase = lds_u + W_OFF + (uint32)(lane * 8);
      const uint32 xbase =
          lds_u + X_OFF + (uint32)((kt & 1) * X_BUF_STR) + (uint32)(lane * 8);
#pragma unroll
      for (int li = 0; li < 4; ++li) {
        TRREAD(ah[li][0], wbase + (uint32)((wl * 4 + li) * SUBT));
        TRREAD(ah[li][1], wbase + (uint32)((16 + wl * 4 + li) * SUBT));
      }
#pragma unroll
      for (int fi = 0; fi < 4; ++fi) {
        TRREAD(bh[fi][0], xbase + (uint32)((wf * 4 + fi) * SUBT));
        TRREAD(bh[fi][1], xbase + (uint32)((8 + wf * 4 + fi) * SUBT));
      }
      LGKM_FENCE();
      __builtin_amdgcn_sched_barrier(0);  // rule #18: nothing hoists above
    }
    // all waves' LDS reads complete -> safe to overwrite W / X[(kt+1)&1]
    if (kt + 1 < NT) BAR();

#pragma unroll
    for (int li = 0; li < 4; ++li) {
      s16x8 af = __builtin_shufflevector(ah[li][0], ah[li][1],
                                         0, 1, 2, 3, 4, 5, 6, 7);
#pragma unroll
      for (int fi = 0; fi < 4; ++fi) {
        s16x8 bf = __builtin_shufflevector(bh[fi][0], bh[fi][1],
                                           0, 1, 2, 3, 4, 5, 6, 7);
        acc[li][fi] =
            __builtin_amdgcn_mfma_f32_16x16x32_bf16(af, bf, acc[li][fi], 0, 0, 0);
      }
    }
    __builtin_amdgcn_sched_barrier(0);  // keep waits/masks below MFMAs

    // ---- write W(kt+1) and X(kt+1); one BAR publishes both ----
    if (kt + 1 < NT) {
      s16x8 m0, m1;
#pragma unroll
      for (int i = 0; i < 8; ++i) {
        const unsigned char a0 = (unsigned char)(jl80 >> (8 * i));
        const unsigned char a1 = (unsigned char)(jl81 >> (8 * i));
        m0[i] = (pjk != 0 && a0 == pjk) ? pv0[i] : (short)0;
        m1[i] = (pjk != 0 && a1 == pjk) ? pv1[i] : (short)0;
      }
      *(s16x8*)(smem + W_OFF + wwr_base) = m0;
      *(s16x8*)(smem + W_OFF + wwr_base + 16) = m1;

      s16x8 pk;  // vmcnt wait for p0/p1 lands here, after the MFMAs
#pragma unroll
      for (int j = 0; j < 4; ++j) {
        pk[j]     = (short)f2bf(p0[j]);
        pk[j + 4] = (short)f2bf(p1[j]);
      }
      *(s16x8*)(smem + X_OFF + ((kt + 1) & 1) * X_BUF_STR + xdst_in) = pk;
      BAR();  // W(kt+1) + X(kt+1) visible before next iteration's tr_reads
    }
  }

  // ---- epilogue: out = x + relu(y); residual re-read from global (L3) ----
  const int g4   = (lane >> 4) * 4;
  const int fcol = lane & 15;
#pragma unroll
  for (int li = 0; li < 4; ++li) {
    const int l0 = (wl * 4 + li) * 16 + g4;
#pragma unroll
    for (int fi = 0; fi < 4; ++fi) {
      const int f = (wf * 4 + fi) * 16 + fcol;
      const float* xp = x + ((b * N_ + l0) * T_ + t) * F_ + f;
      float* op = out + ((b * N_ + l0) * T_ + t) * F_ + f;
#pragma unroll
      for (int r = 0; r < 4; ++r) {
        float y = acc[li][fi][r];
        y = y > 0.f ? y : 0.f;
        op[r * (T_ * F_)] = xp[r * (T_ * F_)] + y;
      }
    }
  }
}

extern "C" void kernel_launch(void* const* d_in, const int* in_sizes, int n_in,
                              void* d_out, int out_size, void* d_ws,
                              size_t ws_size, hipStream_t stream) {
  (void)in_sizes; (void)n_in; (void)out_size; (void)ws_size;
  const float* x     = (const float*)d_in[0];
  const int*   entry = (const int*)d_in[1];
  const int*   job   = (const int*)d_in[2];
  // d_in[3] rackid unused; d_in[5..7] bias/gamma/beta dead in reference math
  const float* fw    = (const float*)d_in[4];
  unsigned short* fwTb = (unsigned short*)d_ws;  // 128 KB scratch

  hipLaunchKernelGGL(wtrans_kernel, dim3(N_), dim3(N_), 0, stream, fw, fwTb);
  hipLaunchKernelGGL(fused_kernel, dim3(B_ * T_), dim3(512), 0, stream,
                     x, entry, job, (const unsigned short*)fwTb, (float*)d_out);
}

// Round 8
// 90.270 us; speedup vs baseline: 1.0253x; 1.0253x over previous
//
#include <hip/hip_runtime.h>
#include <stdint.h>

typedef float  f32x4 __attribute__((ext_vector_type(4)));
typedef short  s16x8 __attribute__((ext_vector_type(8)));
typedef short  s16x4 __attribute__((ext_vector_type(4)));
typedef unsigned int uint32;

#define B_ 16
#define N_ 256
#define T_ 64
#define F_ 128
#define KT 32
#define NT 8   /* K tiles: 8*32 = 256 */
#define NF 64  /* f columns per block (f-split x2) */

// LDS (bytes), UNPADDED 16x16 bf16 subtiles (512 B).
// X: ALL 8 k-tiles resident, 256k x 64f bf16 = 32 KB (residual source).
// W: ONE 256l x 32k tile = 16 KB (register-prefetched, R6-proven).
// Total 49152 -> 3 blocks/CU; 256-thread blocks DO co-schedule (R3: 40%).
#define SUBT 512
#define X_TILE_STR (8 * SUBT)               /* 4096 per k-tile (2kb x 4fb) */
#define X_OFF 0
#define W_OFF (NT * X_TILE_STR)             /* 32768 */
#define LDS_SZ (W_OFF + 32 * SUBT)          /* 49152 */

#define TRREAD(dst, addr) \
  asm volatile("ds_read_b64_tr_b16 %0, %1" : "=v"(dst) : "v"(addr))

#define LGKM_FENCE() asm volatile("s_waitcnt lgkmcnt(0)" ::: "memory")
#define BAR()                                    \
  do {                                           \
    LGKM_FENCE();                                \
    __builtin_amdgcn_s_barrier();                \
    asm volatile("" ::: "memory");               \
  } while (0)

__device__ __forceinline__ unsigned short f2bf(float f) {
  union { float f; unsigned int u; } v; v.f = f;
  unsigned int u = v.u;
  return (unsigned short)((u + 0x7fffu + ((u >> 16) & 1u)) >> 16);
}
__device__ __forceinline__ float bf2f(unsigned short h) {
  union { unsigned int u; float f; } v; v.u = ((unsigned int)h) << 16;
  return v.f;
}

// fwTb[c][l] = bf16(full_weight[l][c])  (256x256, lives in d_ws, L2-resident)
__global__ void wtrans_kernel(const float* __restrict__ fw,
                              unsigned short* __restrict__ fwTb) {
  int c = blockIdx.x;
  int l = threadIdx.x;
  fwTb[c * N_ + l] = f2bf(fw[l * N_ + c]);
}

// launch_bounds(256, 2): 256-VGPR cap; natural alloc ~110-125 -> 4 waves/SIMD
// permitted; LDS (49152) caps co-residency at 3 blocks/CU. DO NOT use
// (256,4): it clamped to 64 VGPR and spilled the 64-reg accumulator (R3).
__global__ __launch_bounds__(256, 2) void fused_kernel(
    const float* __restrict__ x,
    const int* __restrict__ entry,
    const int* __restrict__ job,
    const unsigned short* __restrict__ fwTb,
    float* __restrict__ out) {
  __shared__ __align__(16) char smem[LDS_SZ];
  const uint32 lds_u = (uint32)(uintptr_t)(&smem[0]);

  const int tid = threadIdx.x;
  const int bid = blockIdx.x;
  const int b  = bid >> 7;
  const int t  = (bid >> 1) & 63;
  const int fh = bid & 1;            // f-half: cols [fh*64, fh*64+64)

  const int wk  = tid & 31;   // this thread's k-column within every tile
  const int wlg = tid >> 5;   // 0..7; thread owns l-groups wlg and wlg+8

  // ---- issue per-thread E/J id loads FIRST (oldest in vmcnt queue) ----
  int er[8], jr[8], jlrA[16], jlrB[16];
#pragma unroll
  for (int i = 0; i < 8; ++i) {
    er[i] = entry[(b * N_ + i * KT + wk) * T_ + t];
    jr[i] = job[(b * N_ + i * KT + wk) * T_ + t];
  }
#pragma unroll
  for (int i = 0; i < 16; ++i) {
    jlrA[i] = job[(b * N_ + wlg * 16 + i) * T_ + t];
    jlrB[i] = job[(b * N_ + (wlg + 8) * 16 + i) * T_ + t];
  }

  // ---- issue ALL X loads (8 tiles x 2 f32x4/thread; deep HBM queue) ----
  const int xk  = tid >> 3;              // 0..31 (k offset within a tile)
  const int xf0 = (tid & 7) << 3;        // 0..56 (f offset within the half)
  const float* xsrc = x + ((b * N_ + xk) * T_ + t) * F_ + fh * NF + xf0;
#define XLD(i)                                                            \
  f32x4 q##i##a = *(const f32x4*)(xsrc + (i) * (KT * T_ * F_));           \
  f32x4 q##i##b = *(const f32x4*)(xsrc + (i) * (KT * T_ * F_) + 4);
  XLD(0) XLD(1) XLD(2) XLD(3) XLD(4) XLD(5) XLD(6) XLD(7)
#undef XLD

  // ---- pack ids into registers (waits only on the early id loads) ----
  uint32 ep0 = 0, ep1 = 0, jp0 = 0, jp1 = 0;
#pragma unroll
  for (int i = 0; i < 4; ++i) {
    ep0 |= ((uint32)(er[i] & 255)) << (8 * i);
    ep1 |= ((uint32)(er[i + 4] & 255)) << (8 * i);
    jp0 |= ((uint32)(jr[i] & 255)) << (8 * i);
    jp1 |= ((uint32)(jr[i + 4] & 255)) << (8 * i);
  }
  uint64_t jlA0 = 0, jlA1 = 0, jlB0 = 0, jlB1 = 0;
#pragma unroll
  for (int i = 0; i < 8; ++i) {
    jlA0 |= ((uint64_t)(jlrA[i] & 255)) << (8 * i);
    jlA1 |= ((uint64_t)(jlrA[i + 8] & 255)) << (8 * i);
    jlB0 |= ((uint64_t)(jlrB[i] & 255)) << (8 * i);
    jlB1 |= ((uint64_t)(jlrB[i + 8] & 255)) << (8 * i);
  }

  // ---- W(0) gather from L2 + mask + store (2 l-groups per thread) ----
  const uint32 wwrA =
      (uint32)(((wk >> 4) * 16 + wlg) * SUBT + (wk & 15) * 32);
  const uint32 wwrB =
      (uint32)(((wk >> 4) * 16 + wlg + 8) * SUBT + (wk & 15) * 32);
  {
    const int ev = (int)(ep0 & 255);
    const unsigned char gjk = (unsigned char)(jp0 & 255);
    const unsigned short* wrow = fwTb + ev * N_;
    s16x8 gA0 = *(const s16x8*)(wrow + wlg * 16);
    s16x8 gA1 = *(const s16x8*)(wrow + wlg * 16 + 8);
    s16x8 gB0 = *(const s16x8*)(wrow + (wlg + 8) * 16);
    s16x8 gB1 = *(const s16x8*)(wrow + (wlg + 8) * 16 + 8);
    s16x8 mA0, mA1, mB0, mB1;
#pragma unroll
    for (int i = 0; i < 8; ++i) {
      const unsigned char a0 = (unsigned char)(jlA0 >> (8 * i));
      const unsigned char a1 = (unsigned char)(jlA1 >> (8 * i));
      const unsigned char b0 = (unsigned char)(jlB0 >> (8 * i));
      const unsigned char b1 = (unsigned char)(jlB1 >> (8 * i));
      mA0[i] = (gjk != 0 && a0 == gjk) ? gA0[i] : (short)0;
      mA1[i] = (gjk != 0 && a1 == gjk) ? gA1[i] : (short)0;
      mB0[i] = (gjk != 0 && b0 == gjk) ? gB0[i] : (short)0;
      mB1[i] = (gjk != 0 && b1 == gjk) ? gB1[i] : (short)0;
    }
    *(s16x8*)(smem + W_OFF + wwrA) = mA0;
    *(s16x8*)(smem + W_OFF + wwrA + 16) = mA1;
    *(s16x8*)(smem + W_OFF + wwrB) = mB0;
    *(s16x8*)(smem + W_OFF + wwrB + 16) = mB1;
  }

  // ---- X convert + stage, all 8 tiles ([k16][f16] subtiles, 2kb x 4fb) ----
  const uint32 xdst_in = (uint32)((((xk >> 4) * 4 + (xf0 >> 4)) * SUBT) +
                                  ((xk & 15) * 32) + ((xf0 & 15) * 2));
#define XST(i)                                                            \
  {                                                                       \
    s16x8 pk;                                                             \
    _Pragma("unroll") for (int _j = 0; _j < 4; ++_j) {                    \
      pk[_j]     = (short)f2bf(q##i##a[_j]);                              \
      pk[_j + 4] = (short)f2bf(q##i##b[_j]);                              \
    }                                                                     \
    *(s16x8*)(smem + X_OFF + (i) * X_TILE_STR + xdst_in) = pk;            \
  }
  XST(0) XST(1) XST(2) XST(3) XST(4) XST(5) XST(6) XST(7)
#undef XST
  BAR();  // X fully staged + W(0) ready

  const int lane = tid & 63;
  const int wl   = tid >> 6;  // wave id 0..3 = wave's 64-l sub-tile

  f32x4 acc[4][4];
#pragma unroll
  for (int i = 0; i < 4; ++i)
#pragma unroll
    for (int j = 0; j < 4; ++j) acc[i][j] = (f32x4){0.f, 0.f, 0.f, 0.f};

  for (int kt = 0; kt < NT; ++kt) {
    // ---- prefetch W(kt+1) gather into regs (ids from regs, no LDS dep) ----
    s16x8 pA0, pA1, pB0, pB1;
    unsigned char pjk = 0;
    if (kt + 1 < NT) {
      const uint32 esel = (kt + 1 < 4) ? ep0 : ep1;
      const uint32 jsel = (kt + 1 < 4) ? jp0 : jp1;
      const int sh = ((kt + 1) & 3) * 8;
      const int ev = (int)((esel >> sh) & 255);
      pjk = (unsigned char)((jsel >> sh) & 255);
      const unsigned short* wrow = fwTb + ev * N_;
      pA0 = *(const s16x8*)(wrow + wlg * 16);
      pA1 = *(const s16x8*)(wrow + wlg * 16 + 8);
      pB0 = *(const s16x8*)(wrow + (wlg + 8) * 16);
      pB1 = *(const s16x8*)(wrow + (wlg + 8) * 16 + 8);
    }

    // ---- fragments: W from the single buffer, X from resident tile kt ----
    s16x4 ah[4][2], bh[4][2];
    {
      const uint32 wbase = lds_u + W_OFF + (uint32)(lane * 8);
      const uint32 xbase =
          lds_u + X_OFF + (uint32)(kt * X_TILE_STR) + (uint32)(lane * 8);
#pragma unroll
      for (int li = 0; li < 4; ++li) {
        TRREAD(ah[li][0], wbase + (uint32)((wl * 4 + li) * SUBT));
        TRREAD(ah[li][1], wbase + (uint32)((16 + wl * 4 + li) * SUBT));
      }
#pragma unroll
      for (int fi = 0; fi < 4; ++fi) {
        TRREAD(bh[fi][0], xbase + (uint32)(fi * SUBT));
        TRREAD(bh[fi][1], xbase + (uint32)((4 + fi) * SUBT));
      }
      LGKM_FENCE();
      __builtin_amdgcn_sched_barrier(0);  // rule #18: nothing hoists above
    }
    // all waves' W reads complete -> safe to overwrite W after this BAR
    if (kt + 1 < NT) BAR();

#pragma unroll
    for (int li = 0; li < 4; ++li) {
      s16x8 af = __builtin_shufflevector(ah[li][0], ah[li][1],
                                         0, 1, 2, 3, 4, 5, 6, 7);
#pragma unroll
      for (int fi = 0; fi < 4; ++fi) {
        s16x8 bf = __builtin_shufflevector(bh[fi][0], bh[fi][1],
                                           0, 1, 2, 3, 4, 5, 6, 7);
        acc[li][fi] =
            __builtin_amdgcn_mfma_f32_16x16x32_bf16(af, bf, acc[li][fi], 0, 0, 0);
      }
    }
    __builtin_amdgcn_sched_barrier(0);  // keep gather-wait/mask below MFMAs

    // ---- mask + write W(kt+1) into the (single) buffer ----
    if (kt + 1 < NT) {
      s16x8 mA0, mA1, mB0, mB1;
#pragma unroll
      for (int i = 0; i < 8; ++i) {
        const unsigned char a0 = (unsigned char)(jlA0 >> (8 * i));
        const unsigned char a1 = (unsigned char)(jlA1 >> (8 * i));
        const unsigned char b0 = (unsigned char)(jlB0 >> (8 * i));
        const unsigned char b1 = (unsigned char)(jlB1 >> (8 * i));
        mA0[i] = (pjk != 0 && a0 == pjk) ? pA0[i] : (short)0;
        mA1[i] = (pjk != 0 && a1 == pjk) ? pA1[i] : (short)0;
        mB0[i] = (pjk != 0 && b0 == pjk) ? pB0[i] : (short)0;
        mB1[i] = (pjk != 0 && b1 == pjk) ? pB1[i] : (short)0;
      }
      *(s16x8*)(smem + W_OFF + wwrA) = mA0;
      *(s16x8*)(smem + W_OFF + wwrA + 16) = mA1;
      *(s16x8*)(smem + W_OFF + wwrB) = mB0;
      *(s16x8*)(smem + W_OFF + wwrB + 16) = mB1;
      BAR();  // W(kt+1) visible before next iteration's tr_reads
    }
  }

  // ---- epilogue: out = x + relu(y); residual from resident X LDS ----
  const int g4   = (lane >> 4) * 4;
  const int fcol = lane & 15;
#pragma unroll
  for (int li = 0; li < 4; ++li) {
    const int Lb = wl * 4 + li;  // 16-row l-block 0..15 (== k-block)
    const uint32 rb = lds_u + X_OFF + (uint32)((Lb >> 1) * X_TILE_STR +
                       ((Lb & 1) * 4) * SUBT + lane * 8);
    s16x4 xr[4];
#pragma unroll
    for (int fi = 0; fi < 4; ++fi) {
      TRREAD(xr[fi], rb + (uint32)(fi * SUBT));
    }
    LGKM_FENCE();
    __builtin_amdgcn_sched_barrier(0);
    const int l0 = Lb * 16 + g4;
#pragma unroll
    for (int fi = 0; fi < 4; ++fi) {
      const int f = fh * NF + fi * 16 + fcol;
      float* op = out + ((b * N_ + l0) * T_ + t) * F_ + f;
#pragma unroll
      for (int r = 0; r < 4; ++r) {
        float y = acc[li][fi][r];
        y = y > 0.f ? y : 0.f;
        op[r * (T_ * F_)] = bf2f((unsigned short)xr[fi][r]) + y;
      }
    }
  }
}

extern "C" void kernel_launch(void* const* d_in, const int* in_sizes, int n_in,
                              void* d_out, int out_size, void* d_ws,
                              size_t ws_size, hipStream_t stream) {
  (void)in_sizes; (void)n_in; (void)out_size; (void)ws_size;
  const float* x     = (const float*)d_in[0];
  const int*   entry = (const int*)d_in[1];
  const int*   job   = (const int*)d_in[2];
  // d_in[3] rackid unused; d_in[5..7] bias/gamma/beta dead in reference math
  const float* fw    = (const float*)d_in[4];
  unsigned short* fwTb = (unsigned short*)d_ws;  // 128 KB scratch

  hipLaunchKernelGGL(wtrans_kernel, dim3(N_), dim3(N_), 0, stream, fw, fwTb);
  hipLaunchKernelGGL(fused_kernel, dim3(B_ * T_ * 2), dim3(256), 0, stream,
                     x, entry, job, (const unsigned short*)fwTb, (float*)d_out);
}

// Round 9
// 89.079 us; speedup vs baseline: 1.0390x; 1.0134x over previous
//
#include <hip/hip_runtime.h>
#include <stdint.h>

typedef float  f32x4 __attribute__((ext_vector_type(4)));
typedef short  s16x8 __attribute__((ext_vector_type(8)));
typedef short  s16x4 __attribute__((ext_vector_type(4)));
typedef unsigned int uint32;

#define B_ 16
#define N_ 256
#define T_ 64
#define F_ 128
#define KT 32
#define NT 8      /* K tiles: 8*32 = 256 */
#define NTILES 4  /* (b,t) tiles per persistent block; grid = 1024/NTILES */

// LDS (bytes), UNPADDED 16x16 bf16 subtiles (512 B).
// X: TWO full all-K buffers (2 x 64 KB) - current tile (residual source)
//    and next tile (filled by the cross-tile pipeline).
// W: ONE 256l x 32k tile (16 KB), register-prefetched (R6-proven).
// Total 147456 -> 1 block/CU BY DESIGN (co-residency never materialized
// in R1-R8; overlap comes from the in-block cross-tile pipeline instead).
#define SUBT 512
#define X_TILE_STR (16 * SUBT)              /* 8192 per k-tile */
#define X_BUFSZ (NT * X_TILE_STR)           /* 65536 per tile buffer */
#define X_OFF 0
#define W_OFF (2 * X_BUFSZ)                 /* 131072 */
#define LDS_SZ (W_OFF + 32 * SUBT)          /* 147456 */

#define TRREAD(dst, addr) \
  asm volatile("ds_read_b64_tr_b16 %0, %1" : "=v"(dst) : "v"(addr))

#define LGKM_FENCE() asm volatile("s_waitcnt lgkmcnt(0)" ::: "memory")
#define BAR()                                    \
  do {                                           \
    LGKM_FENCE();                                \
    __builtin_amdgcn_s_barrier();                \
    asm volatile("" ::: "memory");               \
  } while (0)

__device__ __forceinline__ unsigned short f2bf(float f) {
  union { float f; unsigned int u; } v; v.f = f;
  unsigned int u = v.u;
  return (unsigned short)((u + 0x7fffu + ((u >> 16) & 1u)) >> 16);
}
__device__ __forceinline__ float bf2f(unsigned short h) {
  union { unsigned int u; float f; } v; v.u = ((unsigned int)h) << 16;
  return v.f;
}

// fwTb[c][l] = bf16(full_weight[l][c])  (256x256, lives in d_ws, L2-resident)
__global__ void wtrans_kernel(const float* __restrict__ fw,
                              unsigned short* __restrict__ fwTb) {
  int c = blockIdx.x;
  int l = threadIdx.x;
  fwTb[c * N_ + l] = f2bf(fw[l * N_ + c]);
}

// launch_bounds(512, 2): 256-VGPR cap; natural alloc ~110-125, no spill.
// DO NOT raise the 2nd arg: (512,4)/(256,4) clamp to 64 VGPR -> the 64-reg
// accumulator spills -> 3-5x slowdown (measured R2/R3/R5).
__global__ __launch_bounds__(512, 2) void fused_kernel(
    const float* __restrict__ x,
    const int* __restrict__ entry,
    const int* __restrict__ job,
    const unsigned short* __restrict__ fwTb,
    float* __restrict__ out) {
  __shared__ __align__(16) char smem[LDS_SZ];
  const uint32 lds_u = (uint32)(uintptr_t)(&smem[0]);

  const int tid = threadIdx.x;
  int tile = blockIdx.x * NTILES;  // this block owns tiles [tile, tile+NTILES)
  int b = tile >> 6;
  int t = tile & 63;

  const int wk  = tid & 31;   // this thread's k-column within every tile
  const int wlg = tid >> 5;   // this thread's 16-row l group (0..15)
  const int xk  = tid >> 4;          // 0..31 (k offset within a k-tile)
  const int xf0 = (tid & 15) << 3;   // 0,8,...,120
  const uint32 xdst_in = (uint32)((((xk >> 4) * 8 + (xf0 >> 4)) * SUBT) +
                                  ((xk & 15) * 32) + ((xf0 & 15) * 2));
  const uint32 wwr_base =
      (uint32)(((wk >> 4) * 16 + wlg) * SUBT + (wk & 15) * 32);

  // ================= first-tile prologue (R4-proven) =================
  int er[8], jr[8], jlr[16];
#pragma unroll
  for (int i = 0; i < 8; ++i) {
    er[i] = entry[(b * N_ + i * KT + wk) * T_ + t];
    jr[i] = job[(b * N_ + i * KT + wk) * T_ + t];
  }
#pragma unroll
  for (int i = 0; i < 16; ++i)
    jlr[i] = job[(b * N_ + wlg * 16 + i) * T_ + t];

  const float* xsrc = x + ((b * N_ + xk) * T_ + t) * F_ + xf0;
#define XLD(i)                                                            \
  f32x4 q##i##a = *(const f32x4*)(xsrc + (i) * (KT * T_ * F_));           \
  f32x4 q##i##b = *(const f32x4*)(xsrc + (i) * (KT * T_ * F_) + 4);
  XLD(0) XLD(1) XLD(2) XLD(3) XLD(4) XLD(5) XLD(6) XLD(7)
#undef XLD

  uint32 ep0 = 0, ep1 = 0, jp0 = 0, jp1 = 0;
#pragma unroll
  for (int i = 0; i < 4; ++i) {
    ep0 |= ((uint32)(er[i] & 255)) << (8 * i);
    ep1 |= ((uint32)(er[i + 4] & 255)) << (8 * i);
    jp0 |= ((uint32)(jr[i] & 255)) << (8 * i);
    jp1 |= ((uint32)(jr[i + 4] & 255)) << (8 * i);
  }
  uint64_t jl80 = 0, jl81 = 0;
#pragma unroll
  for (int i = 0; i < 8; ++i) {
    jl80 |= ((uint64_t)(jlr[i] & 255)) << (8 * i);
    jl81 |= ((uint64_t)(jlr[i + 8] & 255)) << (8 * i);
  }

  {  // W(0) of tile 0: gather + mask + write
    const int ev = (int)(ep0 & 255);
    const unsigned char gjk = (unsigned char)(jp0 & 255);
    const unsigned short* wrow = fwTb + ev * N_ + wlg * 16;
    s16x8 gv0 = *(const s16x8*)(wrow);
    s16x8 gv1 = *(const s16x8*)(wrow + 8);
    s16x8 m0, m1;
#pragma unroll
    for (int i = 0; i < 8; ++i) {
      const unsigned char a0 = (unsigned char)(jl80 >> (8 * i));
      const unsigned char a1 = (unsigned char)(jl81 >> (8 * i));
      m0[i] = (gjk != 0 && a0 == gjk) ? gv0[i] : (short)0;
      m1[i] = (gjk != 0 && a1 == gjk) ? gv1[i] : (short)0;
    }
    *(s16x8*)(smem + W_OFF + wwr_base) = m0;
    *(s16x8*)(smem + W_OFF + wwr_base + 16) = m1;
  }

#define XST(i)                                                            \
  {                                                                       \
    s16x8 pk;                                                             \
    _Pragma("unroll") for (int _j = 0; _j < 4; ++_j) {                    \
      pk[_j]     = (short)f2bf(q##i##a[_j]);                              \
      pk[_j + 4] = (short)f2bf(q##i##b[_j]);                              \
    }                                                                     \
    *(s16x8*)(smem + X_OFF + (i) * X_TILE_STR + xdst_in) = pk;            \
  }
  XST(0) XST(1) XST(2) XST(3) XST(4) XST(5) XST(6) XST(7)
#undef XST
  BAR();  // X(tile0) fully staged into buf0 + W(0) ready

  const int lane = tid & 63;
  const int wid  = tid >> 6;
  const int wl   = wid & 3;   // wave's 64-l sub-tile (0..3)
  const int wf   = wid >> 2;  // wave's 64-f sub-tile (0..1)

  // next-tile id registers (filled at kt==4 of each tile)
  uint32 nep0 = 0, nep1 = 0, njp0 = 0, njp1 = 0;
  uint64_t njl0 = 0, njl1 = 0;

  // ================= persistent-tile loop =================
  for (int g = 0; g < NTILES; ++g) {
    const uint32 xcur = (uint32)((g & 1) * X_BUFSZ);
    const uint32 xnxt = (uint32)(((g & 1) ^ 1) * X_BUFSZ);
    const bool pf = (g + 1 < NTILES);
    const int ntile = pf ? tile + 1 : tile;
    const int nb = ntile >> 6, ntt = ntile & 63;

    f32x4 acc[4][4];
#pragma unroll
    for (int i = 0; i < 4; ++i)
#pragma unroll
      for (int j = 0; j < 4; ++j) acc[i][j] = (f32x4){0.f, 0.f, 0.f, 0.f};

    f32x4 pvA, pvB;  // next-tile X chunk kt-1, in flight from last iteration
    f32x4 cvA, cvB;  // next-tile X chunk kt, issued this iteration

    for (int kt = 0; kt < NT; ++kt) {
      const bool has_next = (kt < NT - 1) || pf;

      // ---- (1) W prefetch gather ISSUED FIRST (oldest in vmcnt queue,
      //      so consuming it later never drains the younger X loads).
      //      kt<7: W(kt+1) of this tile; kt==7: W(0) of the next tile. ----
      s16x8 wv0, wv1;
      unsigned char wjk = 0;
      uint64_t mj0 = 0, mj1 = 0;
      if (has_next) {
        int ev;
        if (kt < NT - 1) {
          const uint32 esel = (kt + 1 < 4) ? ep0 : ep1;
          const uint32 jsel = (kt + 1 < 4) ? jp0 : jp1;
          const int sh = ((kt + 1) & 3) * 8;
          ev = (int)((esel >> sh) & 255);
          wjk = (unsigned char)((jsel >> sh) & 255);
          mj0 = jl80; mj1 = jl81;
        } else {
          ev = (int)(nep0 & 255);
          wjk = (unsigned char)(njp0 & 255);
          mj0 = njl0; mj1 = njl1;
        }
        const unsigned short* wrow = fwTb + ev * N_ + wlg * 16;
        wv0 = *(const s16x8*)(wrow);
        wv1 = *(const s16x8*)(wrow + 8);
      }

      // ---- (2) next-tile ids at kt==4 (small one-time L2 stall) ----
      if (pf && kt == 4) {
        int e2[8], j2[8], l2[16];
#pragma unroll
        for (int i = 0; i < 8; ++i) {
          e2[i] = entry[(nb * N_ + i * KT + wk) * T_ + ntt];
          j2[i] = job[(nb * N_ + i * KT + wk) * T_ + ntt];
        }
#pragma unroll
        for (int i = 0; i < 16; ++i)
          l2[i] = job[(nb * N_ + wlg * 16 + i) * T_ + ntt];
        nep0 = nep1 = njp0 = njp1 = 0; njl0 = njl1 = 0;
#pragma unroll
        for (int i = 0; i < 4; ++i) {
          nep0 |= ((uint32)(e2[i] & 255)) << (8 * i);
          nep1 |= ((uint32)(e2[i + 4] & 255)) << (8 * i);
          njp0 |= ((uint32)(j2[i] & 255)) << (8 * i);
          njp1 |= ((uint32)(j2[i + 4] & 255)) << (8 * i);
        }
#pragma unroll
        for (int i = 0; i < 8; ++i) {
          njl0 |= ((uint64_t)(l2[i] & 255)) << (8 * i);
          njl1 |= ((uint64_t)(l2[i + 8] & 255)) << (8 * i);
        }
      }

      // ---- (3) issue next-tile X chunk kt loads (consumed NEXT iter) ----
      if (pf) {
        const float* src =
            x + ((nb * N_ + kt * KT + xk) * T_ + ntt) * F_ + xf0;
        cvA = *(const f32x4*)(src);
        cvB = *(const f32x4*)(src + 4);
      }

      // ---- (4) fragments: W from buffer, X from current tile buffer ----
      s16x4 ah[4][2], bh[4][2];
      {
        const uint32 wbase = lds_u + W_OFF + (uint32)(lane * 8);
        const uint32 xbase = lds_u + X_OFF + xcur +
                             (uint32)(kt * X_TILE_STR) + (uint32)(lane * 8);
#pragma unroll
        for (int li = 0; li < 4; ++li) {
          TRREAD(ah[li][0], wbase + (uint32)((wl * 4 + li) * SUBT));
          TRREAD(ah[li][1], wbase + (uint32)((16 + wl * 4 + li) * SUBT));
        }
#pragma unroll
        for (int fi = 0; fi < 4; ++fi) {
          TRREAD(bh[fi][0], xbase + (uint32)((wf * 4 + fi) * SUBT));
          TRREAD(bh[fi][1], xbase + (uint32)((8 + wf * 4 + fi) * SUBT));
        }
        LGKM_FENCE();
        __builtin_amdgcn_sched_barrier(0);  // rule #18
      }
      // all waves' W reads complete -> W buffer may be overwritten below
      if (has_next) BAR();

#pragma unroll
      for (int li = 0; li < 4; ++li) {
        s16x8 af = __builtin_shufflevector(ah[li][0], ah[li][1],
                                           0, 1, 2, 3, 4, 5, 6, 7);
#pragma unroll
        for (int fi = 0; fi < 4; ++fi) {
          s16x8 bf = __builtin_shufflevector(bh[fi][0], bh[fi][1],
                                             0, 1, 2, 3, 4, 5, 6, 7);
          acc[li][fi] = __builtin_amdgcn_mfma_f32_16x16x32_bf16(
              af, bf, acc[li][fi], 0, 0, 0);
        }
      }
      __builtin_amdgcn_sched_barrier(0);  // keep waits/masks below MFMAs

      // ---- (5) convert+write PREVIOUS next-tile X chunk (kt-1):
      //      a full iteration of HBM latency hiding ----
      if (pf && kt >= 1) {
        s16x8 pk;
#pragma unroll
        for (int j = 0; j < 4; ++j) {
          pk[j]     = (short)f2bf(pvA[j]);
          pk[j + 4] = (short)f2bf(pvB[j]);
        }
        *(s16x8*)(smem + X_OFF + xnxt + (uint32)((kt - 1) * X_TILE_STR) +
                  xdst_in) = pk;
      }
      if (pf) { pvA = cvA; pvB = cvB; }

      // ---- (6) mask + write W into the single buffer ----
      if (has_next) {
        s16x8 m0, m1;
#pragma unroll
        for (int i = 0; i < 8; ++i) {
          const unsigned char a0 = (unsigned char)(mj0 >> (8 * i));
          const unsigned char a1 = (unsigned char)(mj1 >> (8 * i));
          m0[i] = (wjk != 0 && a0 == wjk) ? wv0[i] : (short)0;
          m1[i] = (wjk != 0 && a1 == wjk) ? wv1[i] : (short)0;
        }
        *(s16x8*)(smem + W_OFF + wwr_base) = m0;
        *(s16x8*)(smem + W_OFF + wwr_base + 16) = m1;
        BAR();  // publish W (and this iteration's X-chunk write)
      }
    }

    // ---- flush next-tile X chunk 7 ----
    if (pf) {
      s16x8 pk;
#pragma unroll
      for (int j = 0; j < 4; ++j) {
        pk[j]     = (short)f2bf(pvA[j]);
        pk[j + 4] = (short)f2bf(pvB[j]);
      }
      *(s16x8*)(smem + X_OFF + xnxt + (uint32)(7 * X_TILE_STR) + xdst_in) = pk;
    }

    // ---- epilogue: out = x + relu(y); residual from current X buffer ----
    const int g4   = (lane >> 4) * 4;
    const int fcol = lane & 15;
#pragma unroll
    for (int li = 0; li < 4; ++li) {
      const int Lb = wl * 4 + li;  // 16-row l-block 0..15
      const uint32 rb = lds_u + X_OFF + xcur +
                        (uint32)((Lb >> 1) * X_TILE_STR +
                                 ((Lb & 1) * 8) * SUBT + lane * 8);
      s16x4 xr[4];
#pragma unroll
      for (int fi = 0; fi < 4; ++fi) {
        TRREAD(xr[fi], rb + (uint32)((wf * 4 + fi) * SUBT));
      }
      LGKM_FENCE();
      __builtin_amdgcn_sched_barrier(0);
      const int l0 = Lb * 16 + g4;
#pragma unroll
      for (int fi = 0; fi < 4; ++fi) {
        const int f = (wf * 4 + fi) * 16 + fcol;
        float* op = out + ((b * N_ + l0) * T_ + t) * F_ + f;
#pragma unroll
        for (int r = 0; r < 4; ++r) {
          float y = acc[li][fi][r];
          y = y > 0.f ? y : 0.f;
          op[r * (T_ * F_)] = bf2f((unsigned short)xr[fi][r]) + y;
        }
      }
    }

    // ---- tile rotation: publish chunk 7, swap ids, advance (b,t) ----
    if (pf) {
      BAR();
      ep0 = nep0; ep1 = nep1; jp0 = njp0; jp1 = njp1;
      jl80 = njl0; jl81 = njl1;
      tile = ntile; b = nb; t = ntt;
    }
  }
}

extern "C" void kernel_launch(void* const* d_in, const int* in_sizes, int n_in,
                              void* d_out, int out_size, void* d_ws,
                              size_t ws_size, hipStream_t stream) {
  (void)in_sizes; (void)n_in; (void)out_size; (void)ws_size;
  const float* x     = (const float*)d_in[0];
  const int*   entry = (const int*)d_in[1];
  const int*   job   = (const int*)d_in[2];
  // d_in[3] rackid unused; d_in[5..7] bias/gamma/beta dead in reference math
  const float* fw    = (const float*)d_in[4];
  unsigned short* fwTb = (unsigned short*)d_ws;  // 128 KB scratch

  hipLaunchKernelGGL(wtrans_kernel, dim3(N_), dim3(N_), 0, stream, fw, fwTb);
  hipLaunchKernelGGL(fused_kernel, dim3((B_ * T_) / NTILES), dim3(512), 0,
                     stream, x, entry, job, (const unsigned short*)fwTb,
                     (float*)d_out);
}